// Round 11
// baseline (1126.706 us; speedup 1.0000x reference)
//
#include <hip/hip_runtime.h>
#include <math.h>

#define BKS 60      // B*K sequences
#define TL  1000    // T
#define NF  128     // N features
#define SD  12      // state dim S
#define RD  8       // dt rank
#define NCH 32      // scan chunks (last partial: 31*32=992, +8)
#define CLEN 32     // chunk length -> 38.4KB LDS -> 4 blocks/CU
#define NTOK (BKS*TL)
#define MT  64      // GEMM token tile
#define NBLK ((NTOK + MT - 1)/MT)   // 938
#define LNP 129     // cross_ln LDS stride (odd -> conflict-free)
#define XBS 72      // bf16 xs [k][t] stride (144B rows, 16B-aligned)
#define WBS 272     // bf16 wl stride, 256-out kernels (544B rows, 16B-aligned)
#define GWB 136     // bf16 wl stride, 128-out kernels (272B rows)

__device__ __forceinline__ float siluf(float x){ return x / (1.f + __expf(-x)); }
__device__ __forceinline__ float softplusf(float x){
  if (x > 20.f) return x;
  float e = __expf(x);
  return (x < -20.f) ? e : __logf(1.f + e);
}
__device__ __forceinline__ unsigned short f2bf(float f){
  unsigned u = __float_as_uint(f);
  u += 0x7fffu + ((u >> 16) & 1u);     // RNE
  return (unsigned short)(u >> 16);
}
__device__ __forceinline__ float bfl(unsigned u){ return __uint_as_float(u << 16); }
__device__ __forceinline__ float bfh(unsigned u){ return __uint_as_float(u & 0xffff0000u); }

// ---- K0: x (B,N,T,K) -> seq (B*K, T, N), one block per (b,t)
__global__ __launch_bounds__(256) void k_ingest(const float* __restrict__ x, float* __restrict__ seq){
  const int b = blockIdx.x / TL, t = blockIdx.x % TL;
  __shared__ float tile[30*NF];
  for (int e = threadIdx.x; e < 30*NF; e += 256){
    int n = e / 30, k = e - n*30;
    tile[k*NF + n] = x[((size_t)(b*NF + n)*TL + t)*30 + k];
  }
  __syncthreads();
  const size_t base = ((size_t)b*30)*TL*NF + (size_t)t*NF;
  for (int e = threadIdx.x; e < 30*NF; e += 256){
    int k = e >> 7, n = e & 127;
    seq[base + (size_t)k*TL*NF + n] = tile[e];
  }
}

// ---- K1: LayerNorm + in_proj, bf16-staged LDS GEMM. 64 tok/block, 256 thr, 8ox8t.
// bf16 staging halves LDS traffic (1 b128 w-read + 1 b128 x-read per kl) and footprint
// (35.8KB -> 4 blocks/CU); fp32 accumulate. R10's fp32 version was LDS-pipe-bound
// (5.04M bank conflicts from 8-way-conflicted fp32 w-reads).
__global__ __launch_bounds__(256) void k_ln_inproj(
    const float* __restrict__ seq, const float* __restrict__ lnw, const float* __restrict__ lnb,
    const float* __restrict__ iw, const float* __restrict__ ib,
    float* __restrict__ xcr, float* __restrict__ zb){
  __shared__ __align__(16) unsigned short xsb[NF*XBS];   // 18432 B, [k][t]
  __shared__ __align__(16) unsigned short wlb[32*WBS];   // 17408 B, [kl][o]
  const int tid = threadIdx.x;
  const int tok0 = blockIdx.x * MT;

  {
    const int j = tid >> 4, l16 = tid & 15;
    for (int it = 0; it < 4; ++it){
      const int t = j + 16*it;
      const int tok = tok0 + t;
      float v[8]; float s = 0.f, s2 = 0.f;
      if (tok < NTOK){
        const float* sp = seq + (size_t)tok*NF;
        #pragma unroll
        for (int i = 0; i < 8; ++i){ float f = sp[l16 + 16*i]; v[i] = f; s += f; s2 += f*f; }
      } else {
        #pragma unroll
        for (int i = 0; i < 8; ++i) v[i] = 0.f;
      }
      #pragma unroll
      for (int m = 1; m < 16; m <<= 1){ s += __shfl_xor(s, m, 64); s2 += __shfl_xor(s2, m, 64); }
      const float mean = s * (1.f/128.f);
      const float rstd = rsqrtf(s2*(1.f/128.f) - mean*mean + 1e-5f);
      #pragma unroll
      for (int i = 0; i < 8; ++i){
        int n = l16 + 16*i;
        xsb[n*XBS + t] = f2bf((v[i]-mean)*rstd*lnw[n] + lnb[n]);
      }
    }
  }

  const int o8 = tid & 31, t8 = tid >> 5;
  float acc[8][8];
  #pragma unroll
  for (int o = 0; o < 8; ++o)
    #pragma unroll
    for (int t = 0; t < 8; ++t) acc[o][t] = 0.f;

  for (int kt = 0; kt < 4; ++kt){           // 4 tiles of 32 kl
    __syncthreads();
    {
      const int ch = tid & 7, row = tid >> 3;   // 8 chunks of 4 kl, 32 rows/pass, 8 passes
      #pragma unroll
      for (int p = 0; p < 8; ++p){
        const int o = row + 32*p;
        const float4 w4 = *(const float4*)(iw + (size_t)o*NF + kt*32 + ch*4);
        const int kl = ch*4;
        wlb[(kl+0)*WBS + o] = f2bf(w4.x);
        wlb[(kl+1)*WBS + o] = f2bf(w4.y);
        wlb[(kl+2)*WBS + o] = f2bf(w4.z);
        wlb[(kl+3)*WBS + o] = f2bf(w4.w);
      }
    }
    __syncthreads();
    for (int kl = 0; kl < 32; ++kl){
      const int kg = kt*32 + kl;
      const uint4 wu = *(const uint4*)&wlb[kl*WBS + o8*8];
      const uint4 xu = *(const uint4*)&xsb[kg*XBS + t8*8];
      const float wv[8] = {bfl(wu.x),bfh(wu.x), bfl(wu.y),bfh(wu.y),
                           bfl(wu.z),bfh(wu.z), bfl(wu.w),bfh(wu.w)};
      const float xv[8] = {bfl(xu.x),bfh(xu.x), bfl(xu.y),bfh(xu.y),
                           bfl(xu.z),bfh(xu.z), bfl(xu.w),bfh(xu.w)};
      #pragma unroll
      for (int o = 0; o < 8; ++o)
        #pragma unroll
        for (int t = 0; t < 8; ++t)
          acc[o][t] = fmaf(wv[o], xv[t], acc[o][t]);
    }
  }

  float bo[8];
  #pragma unroll
  for (int i = 0; i < 8; ++i) bo[i] = ib[o8*8 + i];
  #pragma unroll
  for (int j = 0; j < 8; ++j){
    const int tok = tok0 + t8*8 + j;
    if (tok >= NTOK) break;
    float4 r0, r1;
    r0.x = acc[0][j]+bo[0]; r0.y = acc[1][j]+bo[1]; r0.z = acc[2][j]+bo[2]; r0.w = acc[3][j]+bo[3];
    r1.x = acc[4][j]+bo[4]; r1.y = acc[5][j]+bo[5]; r1.z = acc[6][j]+bo[6]; r1.w = acc[7][j]+bo[7];
    if (o8 < 16){
      float* dst = xcr + (size_t)tok*NF + o8*8;
      *(float4*)dst = r0; *(float4*)(dst+4) = r1;
    } else {
      float* dst = zb + (size_t)tok*NF + (o8*8 - 128);
      *(float4*)dst = r0; *(float4*)(dst+4) = r1;
    }
  }
}

// ---- K2f (fused, R10 known-good shape): conv+silu -> x-proj -> dt/B/C -> scan pass 1.
__global__ __launch_bounds__(256) void k_conv_scan1(
    const float* __restrict__ xcr,
    const float* __restrict__ cw, const float* __restrict__ cb,
    const float* __restrict__ xw, const float* __restrict__ dw, const float* __restrict__ db,
    const float* __restrict__ alog,
    float* __restrict__ xcc, float* __restrict__ dtb,
    float* __restrict__ Bmb, float* __restrict__ Cmb,
    float* __restrict__ ap, float* __restrict__ hfb){
  __shared__ float smem[(CLEN+3)*NF + CLEN*NF + CLEN*32];
  float* sxr  = smem;
  float* sdt  = smem;                      // aliases sxr (written 2 barriers after last sxr read)
  float* sxc  = smem + (CLEN+3)*NF;
  float* sdbc = sxc + CLEN*NF;
  const int bid = blockIdx.x;
  const int sq = bid / NCH, cblk = bid - sq*NCH;
  const int t0 = cblk*CLEN;
  const int lim = (TL - t0 < CLEN) ? (TL - t0) : CLEN;
  const int tid = threadIdx.x;

  for (int e = tid; e < (CLEN+3)*NF; e += 256){
    int r = e >> 7, n = e & 127;
    int t = t0 - 3 + r;
    sxr[e] = (t >= 0 && t < TL) ? xcr[((size_t)sq*TL + t)*NF + n] : 0.f;
  }
  __syncthreads();

  float convv[(CLEN*NF)/256];
  #pragma unroll
  for (int i = 0; i < (CLEN*NF)/256; ++i){
    int e = tid + i*256;
    int r = e >> 7, n = e & 127;
    float a = cb[n];
    #pragma unroll
    for (int k = 0; k < 4; ++k)
      a = fmaf(sxr[(r+k)*NF + n], cw[n*4 + k], a);
    convv[i] = siluf(a);
  }
  __syncthreads();
  #pragma unroll
  for (int i = 0; i < (CLEN*NF)/256; ++i){
    int e = tid + i*256;
    sxc[e] = convv[i];
    if (e < lim*NF) xcc[((size_t)sq*TL + t0)*NF + e] = convv[i];
  }
  __syncthreads();

  {
    const int o = tid & 31, jg = tid >> 5;
    const float4* wr = (const float4*)(xw + (size_t)o*NF);
    float acc[4];
    #pragma unroll
    for (int j = 0; j < 4; ++j) acc[j] = 0.f;
    for (int k4 = 0; k4 < 32; ++k4){
      float4 w4 = wr[k4];
      #pragma unroll
      for (int j = 0; j < 4; ++j){
        float4 x4 = *((const float4*)&sxc[(jg*4 + j)*NF + k4*4]);
        acc[j] = fmaf(w4.x,x4.x, fmaf(w4.y,x4.y, fmaf(w4.z,x4.z, fmaf(w4.w,x4.w, acc[j]))));
      }
    }
    #pragma unroll
    for (int j = 0; j < 4; ++j) sdbc[(jg*4 + j)*32 + o] = acc[j];
  }
  __syncthreads();

  #pragma unroll
  for (int i = 0; i < (CLEN*NF)/256; ++i){
    int e = tid + i*256;
    int r = e >> 7, n = e & 127;
    float acc = db[n];
    #pragma unroll
    for (int q = 0; q < 8; ++q)
      acc = fmaf(sdbc[r*32 + q], dw[n*8 + q], acc);
    float dtv = softplusf(acc);
    sdt[e] = dtv;
    if (e < lim*NF) dtb[((size_t)sq*TL + t0)*NF + e] = dtv;
  }
  for (int e = tid; e < CLEN*2*SD; e += 256){
    int r = e / (2*SD), c = e - r*2*SD;
    if (r < lim){
      float v = sdbc[r*32 + 8 + c];
      size_t tok = (size_t)sq*TL + t0 + r;
      if (c < SD) Bmb[tok*SD + c] = v;
      else        Cmb[tok*SD + (c - SD)] = v;
    }
  }
  __syncthreads();

  {
    const int n = tid & 127, p = tid >> 7;
    float Av[6], h[6], apv[6];
    #pragma unroll
    for (int s = 0; s < 6; ++s){
      Av[s] = -__expf(alog[(size_t)n*SD + p*6 + s]);
      h[s] = 0.f; apv[s] = 1.f;
    }
    for (int tt = 0; tt < lim; ++tt){
      float dtv = sdt[tt*NF + n];
      float dx  = dtv * sxc[tt*NF + n];
      #pragma unroll
      for (int s = 0; s < 6; ++s){
        float Bv = sdbc[tt*32 + 8 + p*6 + s];
        float dA = __expf(dtv*Av[s]);
        h[s] = fmaf(dA, h[s], dx*Bv);
        apv[s] *= dA;
      }
    }
    const size_t base = (size_t)bid*SD*NF + n;
    #pragma unroll
    for (int s = 0; s < 6; ++s){
      ap [base + (p*6+s)*NF] = apv[s];
      hfb[base + (p*6+s)*NF] = h[s];
    }
  }
}

// ---- K3b: sequential combine across chunks
__global__ __launch_bounds__(128) void k_scan_combine(
    const float* __restrict__ ap, const float* __restrict__ hfb, float* __restrict__ hinit){
  const int sq = blockIdx.x;
  const int n = threadIdx.x;
  float h[SD];
  #pragma unroll
  for (int s = 0; s < SD; ++s) h[s] = 0.f;
  for (int c = 0; c < NCH; ++c){
    const size_t base = ((size_t)sq*NCH + c)*SD*NF + n;
    #pragma unroll
    for (int s = 0; s < SD; ++s){
      hinit[base + s*NF] = h[s];
      h[s] = fmaf(ap[base + s*NF], h[s], hfb[base + s*NF]);
    }
  }
}

// ---- K3c: scan pass 2 + gate: yb = (y + Dv*xc)*silu(z)
__global__ __launch_bounds__(128) void k_scan_pass2(
    const float* __restrict__ dtb, const float* __restrict__ xcc,
    const float* __restrict__ Bmb, const float* __restrict__ Cmb,
    const float* __restrict__ alog, const float* __restrict__ hinit,
    const float* __restrict__ zb, const float* __restrict__ Dv,
    float* __restrict__ yb){
  const int bid = blockIdx.x;
  const int sq = bid / NCH, c = bid - sq*NCH;
  const int t0 = c*CLEN;
  const int lim = (TL - t0 < CLEN) ? (TL - t0) : CLEN;
  const int n = threadIdx.x;
  const float4* A4 = (const float4*)(alog + (size_t)n*SD);
  float4 Aa = A4[0], Ab = A4[1], Ac = A4[2];
  float Av[SD] = {Aa.x,Aa.y,Aa.z,Aa.w, Ab.x,Ab.y,Ab.z,Ab.w, Ac.x,Ac.y,Ac.z,Ac.w};
  #pragma unroll
  for (int s = 0; s < SD; ++s) Av[s] = -__expf(Av[s]);
  const float dvn = Dv[n];
  float h[SD];
  const size_t hbase = (size_t)bid*SD*NF + n;
  #pragma unroll
  for (int s = 0; s < SD; ++s) h[s] = hinit[hbase + s*NF];
  const size_t tok0 = (size_t)sq*TL + t0;
  for (int tt = 0; tt < lim; ++tt){
    const size_t tok = tok0 + tt;
    float dtv = dtb[tok*NF + n];
    float xcv = xcc[tok*NF + n];
    float dx  = dtv * xcv;
    const float4* B4 = (const float4*)(Bmb + tok*SD);
    const float4* C4 = (const float4*)(Cmb + tok*SD);
    float4 Ba=B4[0], Bb=B4[1], Bc=B4[2];
    float4 Ca=C4[0], Cb=C4[1], Cc=C4[2];
    float Bv[SD] = {Ba.x,Ba.y,Ba.z,Ba.w, Bb.x,Bb.y,Bb.z,Bb.w, Bc.x,Bc.y,Bc.z,Bc.w};
    float Cv[SD] = {Ca.x,Ca.y,Ca.z,Ca.w, Cb.x,Cb.y,Cb.z,Cb.w, Cc.x,Cc.y,Cc.z,Cc.w};
    float yv = 0.f;
    #pragma unroll
    for (int s = 0; s < SD; ++s){
      float dA = __expf(dtv*Av[s]);
      h[s] = fmaf(dA, h[s], dx*Bv[s]);
      yv = fmaf(h[s], Cv[s], yv);
    }
    float zv = zb[tok*NF + n];
    yb[tok*NF + n] = fmaf(dvn, xcv, yv) * siluf(zv);
  }
}

// ---- K4: seq += yb @ ow^T + ob. bf16-staged. 64 tok/block, 256 thr, 4ox8t.
__global__ __launch_bounds__(256) void k_gate_out(
    const float* __restrict__ yb,
    const float* __restrict__ ow, const float* __restrict__ ob,
    float* __restrict__ seq){
  __shared__ __align__(16) unsigned short xsb[NF*XBS];   // 18432 B, [n][t]
  __shared__ __align__(16) unsigned short wlb[64*GWB];   // 17408 B, [kl][o]
  const int tid = threadIdx.x;
  const int tok0 = blockIdx.x * MT;

  #pragma unroll
  for (int i = 0; i < 8; ++i){
    const int e4 = tid + i*256;
    const int nq = e4 & 31, r = e4 >> 5;
    const int tok = tok0 + r;
    float4 v = make_float4(0.f,0.f,0.f,0.f);
    if (tok < NTOK) v = *(const float4*)(yb + (size_t)tok*NF + nq*4);
    xsb[(nq*4+0)*XBS + r] = f2bf(v.x);
    xsb[(nq*4+1)*XBS + r] = f2bf(v.y);
    xsb[(nq*4+2)*XBS + r] = f2bf(v.z);
    xsb[(nq*4+3)*XBS + r] = f2bf(v.w);
  }

  const int o4 = tid & 31, t8 = tid >> 5;
  float acc[4][8];
  #pragma unroll
  for (int o = 0; o < 4; ++o)
    #pragma unroll
    for (int t = 0; t < 8; ++t) acc[o][t] = 0.f;

  for (int kt = 0; kt < 2; ++kt){           // 2 tiles of 64 kl
    __syncthreads();
    {
      const int ch = tid & 15, row = tid >> 4;   // 16 chunks of 4 kl, 16 rows/pass, 8 passes
      #pragma unroll
      for (int p = 0; p < 8; ++p){
        const int o = row + 16*p;
        const float4 w4 = *(const float4*)(ow + (size_t)o*NF + kt*64 + ch*4);
        const int kl = ch*4;
        wlb[(kl+0)*GWB + o] = f2bf(w4.x);
        wlb[(kl+1)*GWB + o] = f2bf(w4.y);
        wlb[(kl+2)*GWB + o] = f2bf(w4.z);
        wlb[(kl+3)*GWB + o] = f2bf(w4.w);
      }
    }
    __syncthreads();
    for (int kl = 0; kl < 64; ++kl){
      const int kg = kt*64 + kl;
      const uint2 wu = *(const uint2*)&wlb[kl*GWB + o4*4];
      const uint4 xu = *(const uint4*)&xsb[kg*XBS + t8*8];
      const float wv[4] = {bfl(wu.x),bfh(wu.x), bfl(wu.y),bfh(wu.y)};
      const float xv[8] = {bfl(xu.x),bfh(xu.x), bfl(xu.y),bfh(xu.y),
                           bfl(xu.z),bfh(xu.z), bfl(xu.w),bfh(xu.w)};
      #pragma unroll
      for (int o = 0; o < 4; ++o)
        #pragma unroll
        for (int t = 0; t < 8; ++t)
          acc[o][t] = fmaf(wv[o], xv[t], acc[o][t]);
    }
  }

  float bo[4];
  #pragma unroll
  for (int i = 0; i < 4; ++i) bo[i] = ob[o4*4 + i];
  #pragma unroll
  for (int j = 0; j < 8; ++j){
    const int tok = tok0 + t8*8 + j;
    if (tok >= NTOK) break;
    float* dst = seq + (size_t)tok*NF + o4*4;
    float4 s0 = *(float4*)dst;
    s0.x += acc[0][j]+bo[0]; s0.y += acc[1][j]+bo[1];
    s0.z += acc[2][j]+bo[2]; s0.w += acc[3][j]+bo[3];
    *(float4*)dst = s0;
  }
}

// ---- K5a: cross = main @ cb_w^T + cb_b. bf16-staged, k_gate_out structure, seq gather.
__global__ __launch_bounds__(256) void k_cross_gemm(
    const float* __restrict__ seq,
    const float* __restrict__ cbw, const float* __restrict__ cbb,
    float* __restrict__ cross){
  __shared__ __align__(16) unsigned short xsb[NF*XBS];
  __shared__ __align__(16) unsigned short wlb[64*GWB];
  const int tid = threadIdx.x;
  const int tok0 = blockIdx.x * MT;

  #pragma unroll
  for (int i = 0; i < 8; ++i){
    const int e4 = tid + i*256;
    const int nq = e4 & 31, r = e4 >> 5;
    const int tok = tok0 + r;
    float4 v = make_float4(0.f,0.f,0.f,0.f);
    if (tok < NTOK){
      int b = tok / 30000, rr = tok - b*30000;
      int t = rr / 30, k = rr - t*30;
      v = *(const float4*)(seq + ((size_t)(b*30 + k)*TL + t)*NF + nq*4);
    }
    xsb[(nq*4+0)*XBS + r] = f2bf(v.x);
    xsb[(nq*4+1)*XBS + r] = f2bf(v.y);
    xsb[(nq*4+2)*XBS + r] = f2bf(v.z);
    xsb[(nq*4+3)*XBS + r] = f2bf(v.w);
  }

  const int o4 = tid & 31, t8 = tid >> 5;
  float acc[4][8];
  #pragma unroll
  for (int o = 0; o < 4; ++o)
    #pragma unroll
    for (int t = 0; t < 8; ++t) acc[o][t] = 0.f;

  for (int kt = 0; kt < 2; ++kt){
    __syncthreads();
    {
      const int ch = tid & 15, row = tid >> 4;
      #pragma unroll
      for (int p = 0; p < 8; ++p){
        const int o = row + 16*p;
        const float4 w4 = *(const float4*)(cbw + (size_t)o*NF + kt*64 + ch*4);
        const int kl = ch*4;
        wlb[(kl+0)*GWB + o] = f2bf(w4.x);
        wlb[(kl+1)*GWB + o] = f2bf(w4.y);
        wlb[(kl+2)*GWB + o] = f2bf(w4.z);
        wlb[(kl+3)*GWB + o] = f2bf(w4.w);
      }
    }
    __syncthreads();
    for (int kl = 0; kl < 64; ++kl){
      const int kg = kt*64 + kl;
      const uint2 wu = *(const uint2*)&wlb[kl*GWB + o4*4];
      const uint4 xu = *(const uint4*)&xsb[kg*XBS + t8*8];
      const float wv[4] = {bfl(wu.x),bfh(wu.x), bfl(wu.y),bfh(wu.y)};
      const float xv[8] = {bfl(xu.x),bfh(xu.x), bfl(xu.y),bfh(xu.y),
                           bfl(xu.z),bfh(xu.z), bfl(xu.w),bfh(xu.w)};
      #pragma unroll
      for (int o = 0; o < 4; ++o)
        #pragma unroll
        for (int t = 0; t < 8; ++t)
          acc[o][t] = fmaf(wv[o], xv[t], acc[o][t]);
    }
  }

  float bo[4];
  #pragma unroll
  for (int i = 0; i < 4; ++i) bo[i] = cbb[o4*4 + i];
  #pragma unroll
  for (int j = 0; j < 8; ++j){
    const int tok = tok0 + t8*8 + j;
    if (tok >= NTOK) break;
    float4 s0;
    s0.x = acc[0][j]+bo[0]; s0.y = acc[1][j]+bo[1];
    s0.z = acc[2][j]+bo[2]; s0.w = acc[3][j]+bo[3];
    *(float4*)(cross + (size_t)tok*NF + o4*4) = s0;
  }
}

// ---- K5b: LN1 -> gelu -> +main -> LN2 -> transposed write. 32 tokens/block.
__global__ __launch_bounds__(256) void k_cross_ln(
    const float* __restrict__ seq, const float* __restrict__ cross,
    const float* __restrict__ clnw, const float* __restrict__ clnb,
    const float* __restrict__ flnw, const float* __restrict__ flnb,
    float* __restrict__ out){
  __shared__ float fs[32*LNP];
  const int tid = threadIdx.x;
  const int tok0 = blockIdx.x * 32;
  const int j16 = tid >> 4, l16 = tid & 15;

  for (int it = 0; it < 2; ++it){
    const int jj = j16 + 16*it;
    const int tok = tok0 + jj;
    const int b = tok / 30000, rr = tok - b*30000;
    const int t = rr / 30, k = rr - t*30;
    const float* cp = cross + (size_t)tok*NF;
    const float* mp = seq + ((size_t)(b*30 + k)*TL + t)*NF;
    float cv[8]; float s = 0.f, s2 = 0.f;
    #pragma unroll
    for (int i = 0; i < 8; ++i){
      float f = cp[l16 + 16*i]; cv[i] = f; s += f; s2 += f*f;
    }
    #pragma unroll
    for (int m = 1; m < 16; m <<= 1){ s += __shfl_xor(s, m, 64); s2 += __shfl_xor(s2, m, 64); }
    float mu = s * (1.f/128.f);
    float rs = rsqrtf(s2*(1.f/128.f) - mu*mu + 1e-5f);
    float rv[8]; float rsum = 0.f, rsum2 = 0.f;
    #pragma unroll
    for (int i = 0; i < 8; ++i){
      int n = l16 + 16*i;
      float cn = (cv[i] - mu)*rs*clnw[n] + clnb[n];
      float g = 0.5f*cn*(1.f + erff(cn*0.70710678118f));
      float res = mp[n] + g;
      rv[i] = res; rsum += res; rsum2 += res*res;
    }
    #pragma unroll
    for (int m = 1; m < 16; m <<= 1){ rsum += __shfl_xor(rsum, m, 64); rsum2 += __shfl_xor(rsum2, m, 64); }
    float mu2 = rsum * (1.f/128.f);
    float rs2 = rsqrtf(rsum2*(1.f/128.f) - mu2*mu2 + 1e-5f);
    #pragma unroll
    for (int i = 0; i < 8; ++i){
      int n = l16 + 16*i;
      fs[jj*LNP + n] = (rv[i] - mu2)*rs2*flnw[n] + flnb[n];
    }
  }
  __syncthreads();

  #pragma unroll
  for (int i = 0; i < 16; ++i){
    const int e = tid + i*256;
    const int j = e & 31, n = e >> 5;
    const int tok = tok0 + j;
    const int b = tok / 30000, rr = tok - b*30000;
    out[(size_t)(b*NF + n)*30000 + rr] = fs[j*LNP + n];
  }
}

extern "C" void kernel_launch(void* const* d_in, const int* in_sizes, int n_in,
                              void* d_out, int out_size, void* d_ws, size_t ws_size,
                              hipStream_t stream){
  const float* x       = (const float*)d_in[0];
  const float* ln_w    = (const float*)d_in[1];
  const float* ln_b    = (const float*)d_in[2];
  const float* in_w    = (const float*)d_in[3];
  const float* in_b    = (const float*)d_in[4];
  const float* conv_w  = (const float*)d_in[5];
  const float* conv_b  = (const float*)d_in[6];
  const float* xp_w    = (const float*)d_in[7];
  const float* dtp_w   = (const float*)d_in[8];
  const float* dtp_b   = (const float*)d_in[9];
  const float* A_log   = (const float*)d_in[10];
  const float* Dv      = (const float*)d_in[11];
  const float* out_w   = (const float*)d_in[12];
  const float* out_b   = (const float*)d_in[13];
  const float* cb_w    = (const float*)d_in[14];
  const float* cb_b    = (const float*)d_in[15];
  const float* cb_ln_w = (const float*)d_in[16];
  const float* cb_ln_b = (const float*)d_in[17];
  const float* fin_ln_w= (const float*)d_in[18];
  const float* fin_ln_b= (const float*)d_in[19];
  float* out = (float*)d_out;

  const size_t SEQSZ = (size_t)BKS*TL*NF;        // 7,680,000 floats
  const size_t CHSZ  = (size_t)BKS*NF*NCH*SD;    // 2,949,120 floats (NCH=32)
  const size_t BASE  = 6*SEQSZ + 2*(size_t)BKS*TL*SD;   // ~190MB
  float* ws  = (float*)d_ws;
  float* seq = ws;
  float* xcr = ws + SEQSZ;
  float* zb  = ws + 2*SEQSZ;
  float* xcc = ws + 3*SEQSZ;
  float* dtb = ws + 4*SEQSZ;
  float* yb  = ws + 5*SEQSZ;
  float* Bmb = ws + 6*SEQSZ;
  float* Cmb = Bmb + (size_t)BKS*TL*SD;
  if (ws_size < BASE*sizeof(float)) return;

  // Liveness aliasing: ap/hfb -> yb region (2*CHSZ = 5.9M <= SEQSZ); hinit -> xcr;
  // cross -> dtb (dead after last pass2).
  float* ap    = yb;
  float* hfb   = yb + CHSZ;
  float* hinit = xcr;
  float* cross = dtb;

  k_ingest<<<2*TL, 256, 0, stream>>>(x, seq);
  for (int l = 0; l < 4; ++l){
    k_ln_inproj<<<NBLK, 256, 0, stream>>>(seq, ln_w + l*NF, ln_b + l*NF,
        in_w + (size_t)l*2*NF*NF, in_b + l*2*NF, xcr, zb);
    k_conv_scan1<<<BKS*NCH, 256, 0, stream>>>(xcr, conv_w + (size_t)l*NF*4, conv_b + l*NF,
        xp_w + (size_t)l*32*NF, dtp_w + (size_t)l*NF*RD, dtp_b + l*NF,
        A_log + (size_t)l*NF*SD, xcc, dtb, Bmb, Cmb, ap, hfb);
    k_scan_combine<<<BKS, NF, 0, stream>>>(ap, hfb, hinit);
    k_scan_pass2<<<BKS*NCH, NF, 0, stream>>>(dtb, xcc, Bmb, Cmb, A_log + (size_t)l*NF*SD,
        hinit, zb, Dv + l*NF, yb);
    k_gate_out<<<NBLK, 256, 0, stream>>>(yb, out_w + (size_t)l*NF*NF, out_b + l*NF, seq);
  }
  k_cross_gemm<<<NBLK, 256, 0, stream>>>(seq, cb_w, cb_b, cross);
  k_cross_ln<<<NTOK/32, 256, 0, stream>>>(seq, cross, cb_ln_w, cb_ln_b, fin_ln_w, fin_ln_b, out);
}

// Round 12
// 1017.532 us; speedup vs baseline: 1.1073x; 1.1073x over previous
//
#include <hip/hip_runtime.h>
#include <math.h>

#define BKS 60      // B*K sequences
#define TL  1000    // T
#define NF  128     // N features
#define SD  12      // state dim S
#define RD  8       // dt rank
#define NCH 32      // scan chunks (last partial: 31*32=992, +8)
#define CLEN 32     // chunk length -> 38.4KB LDS -> 4 blocks/CU
#define NTOK (BKS*TL)
#define MT  64      // GEMM token tile
#define NBLK ((NTOK + MT - 1)/MT)   // 938
#define XSP 68      // xs [n][t] stride
#define WSP 260     // in_proj w_lds stride (256+4)
#define GWS 132     // 128-out w_lds stride (128+4)
#define LNP 129     // cross_ln LDS stride (odd -> conflict-free)

__device__ __forceinline__ float siluf(float x){ return x / (1.f + __expf(-x)); }
__device__ __forceinline__ float softplusf(float x){
  if (x > 20.f) return x;
  float e = __expf(x);
  return (x < -20.f) ? e : __logf(1.f + e);
}

// ---- K0: x (B,N,T,K) -> seq (B*K, T, N), one block per (b,t)
__global__ __launch_bounds__(256) void k_ingest(const float* __restrict__ x, float* __restrict__ seq){
  const int b = blockIdx.x / TL, t = blockIdx.x % TL;
  __shared__ float tile[30*NF];
  for (int e = threadIdx.x; e < 30*NF; e += 256){
    int n = e / 30, k = e - n*30;
    tile[k*NF + n] = x[((size_t)(b*NF + n)*TL + t)*30 + k];
  }
  __syncthreads();
  const size_t base = ((size_t)b*30)*TL*NF + (size_t)t*NF;
  for (int e = threadIdx.x; e < 30*NF; e += 256){
    int k = e >> 7, n = e & 127;
    seq[base + (size_t)k*TL*NF + n] = tile[e];
  }
}

// ---- K1: LayerNorm + in_proj. 64 tok/block, 256 thr. Output tile SPLIT 4+4:
// thread owns outputs {o8*4..+3} (-> xcr) and {128+o8*4..+3} (-> zb), so both LDS
// w-reads are 16B-lane-stride contiguous float4s (2-way max = free). R10's 8-consecutive
// tile had 32B lane stride -> 4-way conflicts (5.04M). bf16 staging (R11) was worse:
// conflicts UP + unpack VALU. fp32 staging, fp32 accumulate.
__global__ __launch_bounds__(256) void k_ln_inproj(
    const float* __restrict__ seq, const float* __restrict__ lnw, const float* __restrict__ lnb,
    const float* __restrict__ iw, const float* __restrict__ ib,
    float* __restrict__ xcr, float* __restrict__ zb){
  __shared__ float xs[NF*XSP];    // [k][t]
  __shared__ float wl[16*WSP];    // [kl][o]
  const int tid = threadIdx.x;
  const int tok0 = blockIdx.x * MT;

  {
    const int j = tid >> 4, l16 = tid & 15;
    for (int it = 0; it < 4; ++it){
      const int t = j + 16*it;
      const int tok = tok0 + t;
      float v[8]; float s = 0.f, s2 = 0.f;
      if (tok < NTOK){
        const float* sp = seq + (size_t)tok*NF;
        #pragma unroll
        for (int i = 0; i < 8; ++i){ float f = sp[l16 + 16*i]; v[i] = f; s += f; s2 += f*f; }
      } else {
        #pragma unroll
        for (int i = 0; i < 8; ++i) v[i] = 0.f;
      }
      #pragma unroll
      for (int m = 1; m < 16; m <<= 1){ s += __shfl_xor(s, m, 64); s2 += __shfl_xor(s2, m, 64); }
      const float mean = s * (1.f/128.f);
      const float rstd = rsqrtf(s2*(1.f/128.f) - mean*mean + 1e-5f);
      #pragma unroll
      for (int i = 0; i < 8; ++i){
        int n = l16 + 16*i;
        xs[n*XSP + t] = (v[i]-mean)*rstd*lnw[n] + lnb[n];
      }
    }
  }

  const int o8 = tid & 31, t8 = tid >> 5;
  float acc[8][8];
  #pragma unroll
  for (int o = 0; o < 8; ++o)
    #pragma unroll
    for (int t = 0; t < 8; ++t) acc[o][t] = 0.f;

  for (int kt = 0; kt < 8; ++kt){
    __syncthreads();
    {
      const int ch = tid & 3, row = tid >> 2;
      #pragma unroll
      for (int p = 0; p < 4; ++p){
        const int o = row + 64*p;
        const float4 w4 = *(const float4*)(iw + (size_t)o*NF + kt*16 + ch*4);
        const int kl = ch*4;
        wl[(kl+0)*WSP + o] = w4.x;
        wl[(kl+1)*WSP + o] = w4.y;
        wl[(kl+2)*WSP + o] = w4.z;
        wl[(kl+3)*WSP + o] = w4.w;
      }
    }
    __syncthreads();
    for (int kl = 0; kl < 16; ++kl){
      const int kg = kt*16 + kl;
      const float4 wa = *(const float4*)&wl[kl*WSP + o8*4];          // outs o8*4..+3
      const float4 wb = *(const float4*)&wl[kl*WSP + 128 + o8*4];    // outs 128+o8*4..+3
      const float4 xa = *(const float4*)&xs[kg*XSP + t8*8];
      const float4 xb = *(const float4*)&xs[kg*XSP + t8*8 + 4];
      const float wv[8] = {wa.x,wa.y,wa.z,wa.w, wb.x,wb.y,wb.z,wb.w};
      const float xv[8] = {xa.x,xa.y,xa.z,xa.w, xb.x,xb.y,xb.z,xb.w};
      #pragma unroll
      for (int o = 0; o < 8; ++o)
        #pragma unroll
        for (int t = 0; t < 8; ++t)
          acc[o][t] = fmaf(wv[o], xv[t], acc[o][t]);
    }
  }

  float bo[8];
  #pragma unroll
  for (int i = 0; i < 4; ++i){ bo[i] = ib[o8*4 + i]; bo[4+i] = ib[128 + o8*4 + i]; }
  #pragma unroll
  for (int j = 0; j < 8; ++j){
    const int tok = tok0 + t8*8 + j;
    if (tok >= NTOK) break;
    float4 r0, r1;
    r0.x = acc[0][j]+bo[0]; r0.y = acc[1][j]+bo[1]; r0.z = acc[2][j]+bo[2]; r0.w = acc[3][j]+bo[3];
    r1.x = acc[4][j]+bo[4]; r1.y = acc[5][j]+bo[5]; r1.z = acc[6][j]+bo[6]; r1.w = acc[7][j]+bo[7];
    *(float4*)(xcr + (size_t)tok*NF + o8*4) = r0;
    *(float4*)(zb  + (size_t)tok*NF + o8*4) = r1;
  }
}

// ---- K2f (fused, R10 known-good): conv+silu -> x-proj -> dt/B/C -> scan pass 1.
__global__ __launch_bounds__(256) void k_conv_scan1(
    const float* __restrict__ xcr,
    const float* __restrict__ cw, const float* __restrict__ cb,
    const float* __restrict__ xw, const float* __restrict__ dw, const float* __restrict__ db,
    const float* __restrict__ alog,
    float* __restrict__ xcc, float* __restrict__ dtb,
    float* __restrict__ Bmb, float* __restrict__ Cmb,
    float* __restrict__ ap, float* __restrict__ hfb){
  __shared__ float smem[(CLEN+3)*NF + CLEN*NF + CLEN*32];
  float* sxr  = smem;
  float* sdt  = smem;                      // aliases sxr (written 2 barriers after last sxr read)
  float* sxc  = smem + (CLEN+3)*NF;
  float* sdbc = sxc + CLEN*NF;
  const int bid = blockIdx.x;
  const int sq = bid / NCH, cblk = bid - sq*NCH;
  const int t0 = cblk*CLEN;
  const int lim = (TL - t0 < CLEN) ? (TL - t0) : CLEN;
  const int tid = threadIdx.x;

  for (int e = tid; e < (CLEN+3)*NF; e += 256){
    int r = e >> 7, n = e & 127;
    int t = t0 - 3 + r;
    sxr[e] = (t >= 0 && t < TL) ? xcr[((size_t)sq*TL + t)*NF + n] : 0.f;
  }
  __syncthreads();

  float convv[(CLEN*NF)/256];
  #pragma unroll
  for (int i = 0; i < (CLEN*NF)/256; ++i){
    int e = tid + i*256;
    int r = e >> 7, n = e & 127;
    float a = cb[n];
    #pragma unroll
    for (int k = 0; k < 4; ++k)
      a = fmaf(sxr[(r+k)*NF + n], cw[n*4 + k], a);
    convv[i] = siluf(a);
  }
  __syncthreads();
  #pragma unroll
  for (int i = 0; i < (CLEN*NF)/256; ++i){
    int e = tid + i*256;
    sxc[e] = convv[i];
    if (e < lim*NF) xcc[((size_t)sq*TL + t0)*NF + e] = convv[i];
  }
  __syncthreads();

  {
    const int o = tid & 31, jg = tid >> 5;
    const float4* wr = (const float4*)(xw + (size_t)o*NF);
    float acc[4];
    #pragma unroll
    for (int j = 0; j < 4; ++j) acc[j] = 0.f;
    for (int k4 = 0; k4 < 32; ++k4){
      float4 w4 = wr[k4];
      #pragma unroll
      for (int j = 0; j < 4; ++j){
        float4 x4 = *((const float4*)&sxc[(jg*4 + j)*NF + k4*4]);
        acc[j] = fmaf(w4.x,x4.x, fmaf(w4.y,x4.y, fmaf(w4.z,x4.z, fmaf(w4.w,x4.w, acc[j]))));
      }
    }
    #pragma unroll
    for (int j = 0; j < 4; ++j) sdbc[(jg*4 + j)*32 + o] = acc[j];
  }
  __syncthreads();

  #pragma unroll
  for (int i = 0; i < (CLEN*NF)/256; ++i){
    int e = tid + i*256;
    int r = e >> 7, n = e & 127;
    float acc = db[n];
    #pragma unroll
    for (int q = 0; q < 8; ++q)
      acc = fmaf(sdbc[r*32 + q], dw[n*8 + q], acc);
    float dtv = softplusf(acc);
    sdt[e] = dtv;
    if (e < lim*NF) dtb[((size_t)sq*TL + t0)*NF + e] = dtv;
  }
  for (int e = tid; e < CLEN*2*SD; e += 256){
    int r = e / (2*SD), c = e - r*2*SD;
    if (r < lim){
      float v = sdbc[r*32 + 8 + c];
      size_t tok = (size_t)sq*TL + t0 + r;
      if (c < SD) Bmb[tok*SD + c] = v;
      else        Cmb[tok*SD + (c - SD)] = v;
    }
  }
  __syncthreads();

  {
    const int n = tid & 127, p = tid >> 7;
    float Av[6], h[6], apv[6];
    #pragma unroll
    for (int s = 0; s < 6; ++s){
      Av[s] = -__expf(alog[(size_t)n*SD + p*6 + s]);
      h[s] = 0.f; apv[s] = 1.f;
    }
    for (int tt = 0; tt < lim; ++tt){
      float dtv = sdt[tt*NF + n];
      float dx  = dtv * sxc[tt*NF + n];
      #pragma unroll
      for (int s = 0; s < 6; ++s){
        float Bv = sdbc[tt*32 + 8 + p*6 + s];
        float dA = __expf(dtv*Av[s]);
        h[s] = fmaf(dA, h[s], dx*Bv);
        apv[s] *= dA;
      }
    }
    const size_t base = (size_t)bid*SD*NF + n;
    #pragma unroll
    for (int s = 0; s < 6; ++s){
      ap [base + (p*6+s)*NF] = apv[s];
      hfb[base + (p*6+s)*NF] = h[s];
    }
  }
}

// ---- K3b: sequential combine across chunks
__global__ __launch_bounds__(128) void k_scan_combine(
    const float* __restrict__ ap, const float* __restrict__ hfb, float* __restrict__ hinit){
  const int sq = blockIdx.x;
  const int n = threadIdx.x;
  float h[SD];
  #pragma unroll
  for (int s = 0; s < SD; ++s) h[s] = 0.f;
  for (int c = 0; c < NCH; ++c){
    const size_t base = ((size_t)sq*NCH + c)*SD*NF + n;
    #pragma unroll
    for (int s = 0; s < SD; ++s){
      hinit[base + s*NF] = h[s];
      h[s] = fmaf(ap[base + s*NF], h[s], hfb[base + s*NF]);
    }
  }
}

// ---- K3c: scan pass 2 + gate: yb = (y + Dv*xc)*silu(z)
__global__ __launch_bounds__(128) void k_scan_pass2(
    const float* __restrict__ dtb, const float* __restrict__ xcc,
    const float* __restrict__ Bmb, const float* __restrict__ Cmb,
    const float* __restrict__ alog, const float* __restrict__ hinit,
    const float* __restrict__ zb, const float* __restrict__ Dv,
    float* __restrict__ yb){
  const int bid = blockIdx.x;
  const int sq = bid / NCH, c = bid - sq*NCH;
  const int t0 = c*CLEN;
  const int lim = (TL - t0 < CLEN) ? (TL - t0) : CLEN;
  const int n = threadIdx.x;
  const float4* A4 = (const float4*)(alog + (size_t)n*SD);
  float4 Aa = A4[0], Ab = A4[1], Ac = A4[2];
  float Av[SD] = {Aa.x,Aa.y,Aa.z,Aa.w, Ab.x,Ab.y,Ab.z,Ab.w, Ac.x,Ac.y,Ac.z,Ac.w};
  #pragma unroll
  for (int s = 0; s < SD; ++s) Av[s] = -__expf(Av[s]);
  const float dvn = Dv[n];
  float h[SD];
  const size_t hbase = (size_t)bid*SD*NF + n;
  #pragma unroll
  for (int s = 0; s < SD; ++s) h[s] = hinit[hbase + s*NF];
  const size_t tok0 = (size_t)sq*TL + t0;
  for (int tt = 0; tt < lim; ++tt){
    const size_t tok = tok0 + tt;
    float dtv = dtb[tok*NF + n];
    float xcv = xcc[tok*NF + n];
    float dx  = dtv * xcv;
    const float4* B4 = (const float4*)(Bmb + tok*SD);
    const float4* C4 = (const float4*)(Cmb + tok*SD);
    float4 Ba=B4[0], Bb=B4[1], Bc=B4[2];
    float4 Ca=C4[0], Cb=C4[1], Cc=C4[2];
    float Bv[SD] = {Ba.x,Ba.y,Ba.z,Ba.w, Bb.x,Bb.y,Bb.z,Bb.w, Bc.x,Bc.y,Bc.z,Bc.w};
    float Cv[SD] = {Ca.x,Ca.y,Ca.z,Ca.w, Cb.x,Cb.y,Cb.z,Cb.w, Cc.x,Cc.y,Cc.z,Cc.w};
    float yv = 0.f;
    #pragma unroll
    for (int s = 0; s < SD; ++s){
      float dA = __expf(dtv*Av[s]);
      h[s] = fmaf(dA, h[s], dx*Bv[s]);
      yv = fmaf(h[s], Cv[s], yv);
    }
    float zv = zb[tok*NF + n];
    yb[tok*NF + n] = fmaf(dvn, xcv, yv) * siluf(zv);
  }
}

// ---- K4 (known-good): seq += yb @ ow^T + ob. 64 tokens/block, 256 threads, 4ox8t.
__global__ __launch_bounds__(256) void k_gate_out(
    const float* __restrict__ yb,
    const float* __restrict__ ow, const float* __restrict__ ob,
    float* __restrict__ seq){
  __shared__ float xs[NF*XSP];    // [n][t]
  __shared__ float wl[32*GWS];    // [kl][o]
  const int tid = threadIdx.x;
  const int tok0 = blockIdx.x * MT;

  #pragma unroll
  for (int i = 0; i < 8; ++i){
    const int e4 = tid + i*256;
    const int nq = e4 & 31, r = e4 >> 5;
    const int tok = tok0 + r;
    float4 v = make_float4(0.f,0.f,0.f,0.f);
    if (tok < NTOK) v = *(const float4*)(yb + (size_t)tok*NF + nq*4);
    xs[(nq*4+0)*XSP + r] = v.x;
    xs[(nq*4+1)*XSP + r] = v.y;
    xs[(nq*4+2)*XSP + r] = v.z;
    xs[(nq*4+3)*XSP + r] = v.w;
  }

  const int o4 = tid & 31, t8 = tid >> 5;
  float acc[4][8];
  #pragma unroll
  for (int o = 0; o < 4; ++o)
    #pragma unroll
    for (int t = 0; t < 8; ++t) acc[o][t] = 0.f;

  for (int kt = 0; kt < 4; ++kt){
    __syncthreads();
    {
      const int ch = tid & 7, row = tid >> 3;
      #pragma unroll
      for (int p = 0; p < 4; ++p){
        const int o = row + 32*p;
        const float4 w4 = *(const float4*)(ow + (size_t)o*NF + kt*32 + ch*4);
        const int kl = ch*4;
        wl[(kl+0)*GWS + o] = w4.x;
        wl[(kl+1)*GWS + o] = w4.y;
        wl[(kl+2)*GWS + o] = w4.z;
        wl[(kl+3)*GWS + o] = w4.w;
      }
    }
    __syncthreads();
    for (int kl = 0; kl < 32; ++kl){
      const int kg = kt*32 + kl;
      const float4 wa = *(const float4*)&wl[kl*GWS + o4*4];
      const float4 xa = *(const float4*)&xs[kg*XSP + t8*8];
      const float4 xb = *(const float4*)&xs[kg*XSP + t8*8 + 4];
      const float wv[4] = {wa.x,wa.y,wa.z,wa.w};
      const float xv[8] = {xa.x,xa.y,xa.z,xa.w, xb.x,xb.y,xb.z,xb.w};
      #pragma unroll
      for (int o = 0; o < 4; ++o)
        #pragma unroll
        for (int t = 0; t < 8; ++t)
          acc[o][t] = fmaf(wv[o], xv[t], acc[o][t]);
    }
  }

  float bo[4];
  #pragma unroll
  for (int i = 0; i < 4; ++i) bo[i] = ob[o4*4 + i];
  #pragma unroll
  for (int j = 0; j < 8; ++j){
    const int tok = tok0 + t8*8 + j;
    if (tok >= NTOK) break;
    float* dst = seq + (size_t)tok*NF + o4*4;
    float4 s0 = *(float4*)dst;
    s0.x += acc[0][j]+bo[0]; s0.y += acc[1][j]+bo[1];
    s0.z += acc[2][j]+bo[2]; s0.w += acc[3][j]+bo[3];
    *(float4*)dst = s0;
  }
}

// ---- K5a: cross = main @ cb_w^T + cb_b. Exact k_gate_out structure; seq gather staging.
__global__ __launch_bounds__(256) void k_cross_gemm(
    const float* __restrict__ seq,
    const float* __restrict__ cbw, const float* __restrict__ cbb,
    float* __restrict__ cross){
  __shared__ float xs[NF*XSP];    // [n][t]
  __shared__ float wl[32*GWS];    // [kl][o]
  const int tid = threadIdx.x;
  const int tok0 = blockIdx.x * MT;

  #pragma unroll
  for (int i = 0; i < 8; ++i){
    const int e4 = tid + i*256;
    const int nq = e4 & 31, r = e4 >> 5;
    const int tok = tok0 + r;
    float4 v = make_float4(0.f,0.f,0.f,0.f);
    if (tok < NTOK){
      int b = tok / 30000, rr = tok - b*30000;
      int t = rr / 30, k = rr - t*30;
      v = *(const float4*)(seq + ((size_t)(b*30 + k)*TL + t)*NF + nq*4);
    }
    xs[(nq*4+0)*XSP + r] = v.x;
    xs[(nq*4+1)*XSP + r] = v.y;
    xs[(nq*4+2)*XSP + r] = v.z;
    xs[(nq*4+3)*XSP + r] = v.w;
  }

  const int o4 = tid & 31, t8 = tid >> 5;
  float acc[4][8];
  #pragma unroll
  for (int o = 0; o < 4; ++o)
    #pragma unroll
    for (int t = 0; t < 8; ++t) acc[o][t] = 0.f;

  for (int kt = 0; kt < 4; ++kt){
    __syncthreads();
    {
      const int ch = tid & 7, row = tid >> 3;
      #pragma unroll
      for (int p = 0; p < 4; ++p){
        const int o = row + 32*p;
        const float4 w4 = *(const float4*)(cbw + (size_t)o*NF + kt*32 + ch*4);
        const int kl = ch*4;
        wl[(kl+0)*GWS + o] = w4.x;
        wl[(kl+1)*GWS + o] = w4.y;
        wl[(kl+2)*GWS + o] = w4.z;
        wl[(kl+3)*GWS + o] = w4.w;
      }
    }
    __syncthreads();
    for (int kl = 0; kl < 32; ++kl){
      const int kg = kt*32 + kl;
      const float4 wa = *(const float4*)&wl[kl*GWS + o4*4];
      const float4 xa = *(const float4*)&xs[kg*XSP + t8*8];
      const float4 xb = *(const float4*)&xs[kg*XSP + t8*8 + 4];
      const float wv[4] = {wa.x,wa.y,wa.z,wa.w};
      const float xv[8] = {xa.x,xa.y,xa.z,xa.w, xb.x,xb.y,xb.z,xb.w};
      #pragma unroll
      for (int o = 0; o < 4; ++o)
        #pragma unroll
        for (int t = 0; t < 8; ++t)
          acc[o][t] = fmaf(wv[o], xv[t], acc[o][t]);
    }
  }

  float bo[4];
  #pragma unroll
  for (int i = 0; i < 4; ++i) bo[i] = cbb[o4*4 + i];
  #pragma unroll
  for (int j = 0; j < 8; ++j){
    const int tok = tok0 + t8*8 + j;
    if (tok >= NTOK) break;
    float4 s0;
    s0.x = acc[0][j]+bo[0]; s0.y = acc[1][j]+bo[1];
    s0.z = acc[2][j]+bo[2]; s0.w = acc[3][j]+bo[3];
    *(float4*)(cross + (size_t)tok*NF + o4*4) = s0;
  }
}

// ---- K5b: LN1 -> gelu -> +main -> LN2 -> transposed write. 32 tokens/block.
__global__ __launch_bounds__(256) void k_cross_ln(
    const float* __restrict__ seq, const float* __restrict__ cross,
    const float* __restrict__ clnw, const float* __restrict__ clnb,
    const float* __restrict__ flnw, const float* __restrict__ flnb,
    float* __restrict__ out){
  __shared__ float fs[32*LNP];
  const int tid = threadIdx.x;
  const int tok0 = blockIdx.x * 32;
  const int j16 = tid >> 4, l16 = tid & 15;

  for (int it = 0; it < 2; ++it){
    const int jj = j16 + 16*it;
    const int tok = tok0 + jj;
    const int b = tok / 30000, rr = tok - b*30000;
    const int t = rr / 30, k = rr - t*30;
    const float* cp = cross + (size_t)tok*NF;
    const float* mp = seq + ((size_t)(b*30 + k)*TL + t)*NF;
    float cv[8]; float s = 0.f, s2 = 0.f;
    #pragma unroll
    for (int i = 0; i < 8; ++i){
      float f = cp[l16 + 16*i]; cv[i] = f; s += f; s2 += f*f;
    }
    #pragma unroll
    for (int m = 1; m < 16; m <<= 1){ s += __shfl_xor(s, m, 64); s2 += __shfl_xor(s2, m, 64); }
    float mu = s * (1.f/128.f);
    float rs = rsqrtf(s2*(1.f/128.f) - mu*mu + 1e-5f);
    float rv[8]; float rsum = 0.f, rsum2 = 0.f;
    #pragma unroll
    for (int i = 0; i < 8; ++i){
      int n = l16 + 16*i;
      float cn = (cv[i] - mu)*rs*clnw[n] + clnb[n];
      float g = 0.5f*cn*(1.f + erff(cn*0.70710678118f));
      float res = mp[n] + g;
      rv[i] = res; rsum += res; rsum2 += res*res;
    }
    #pragma unroll
    for (int m = 1; m < 16; m <<= 1){ rsum += __shfl_xor(rsum, m, 64); rsum2 += __shfl_xor(rsum2, m, 64); }
    float mu2 = rsum * (1.f/128.f);
    float rs2 = rsqrtf(rsum2*(1.f/128.f) - mu2*mu2 + 1e-5f);
    #pragma unroll
    for (int i = 0; i < 8; ++i){
      int n = l16 + 16*i;
      fs[jj*LNP + n] = (rv[i] - mu2)*rs2*flnw[n] + flnb[n];
    }
  }
  __syncthreads();

  #pragma unroll
  for (int i = 0; i < 16; ++i){
    const int e = tid + i*256;
    const int j = e & 31, n = e >> 5;
    const int tok = tok0 + j;
    const int b = tok / 30000, rr = tok - b*30000;
    out[(size_t)(b*NF + n)*30000 + rr] = fs[j*LNP + n];
  }
}

extern "C" void kernel_launch(void* const* d_in, const int* in_sizes, int n_in,
                              void* d_out, int out_size, void* d_ws, size_t ws_size,
                              hipStream_t stream){
  const float* x       = (const float*)d_in[0];
  const float* ln_w    = (const float*)d_in[1];
  const float* ln_b    = (const float*)d_in[2];
  const float* in_w    = (const float*)d_in[3];
  const float* in_b    = (const float*)d_in[4];
  const float* conv_w  = (const float*)d_in[5];
  const float* conv_b  = (const float*)d_in[6];
  const float* xp_w    = (const float*)d_in[7];
  const float* dtp_w   = (const float*)d_in[8];
  const float* dtp_b   = (const float*)d_in[9];
  const float* A_log   = (const float*)d_in[10];
  const float* Dv      = (const float*)d_in[11];
  const float* out_w   = (const float*)d_in[12];
  const float* out_b   = (const float*)d_in[13];
  const float* cb_w    = (const float*)d_in[14];
  const float* cb_b    = (const float*)d_in[15];
  const float* cb_ln_w = (const float*)d_in[16];
  const float* cb_ln_b = (const float*)d_in[17];
  const float* fin_ln_w= (const float*)d_in[18];
  const float* fin_ln_b= (const float*)d_in[19];
  float* out = (float*)d_out;

  const size_t SEQSZ = (size_t)BKS*TL*NF;        // 7,680,000 floats
  const size_t CHSZ  = (size_t)BKS*NF*NCH*SD;    // 2,949,120 floats (NCH=32)
  const size_t BASE  = 6*SEQSZ + 2*(size_t)BKS*TL*SD;   // ~190MB
  float* ws  = (float*)d_ws;
  float* seq = ws;
  float* xcr = ws + SEQSZ;
  float* zb  = ws + 2*SEQSZ;
  float* xcc = ws + 3*SEQSZ;
  float* dtb = ws + 4*SEQSZ;
  float* yb  = ws + 5*SEQSZ;
  float* Bmb = ws + 6*SEQSZ;
  float* Cmb = Bmb + (size_t)BKS*TL*SD;
  if (ws_size < BASE*sizeof(float)) return;

  // Liveness aliasing: ap/hfb -> yb region (2*CHSZ = 5.9M <= SEQSZ); hinit -> xcr;
  // cross -> dtb (dead after last pass2).
  float* ap    = yb;
  float* hfb   = yb + CHSZ;
  float* hinit = xcr;
  float* cross = dtb;

  k_ingest<<<2*TL, 256, 0, stream>>>(x, seq);
  for (int l = 0; l < 4; ++l){
    k_ln_inproj<<<NBLK, 256, 0, stream>>>(seq, ln_w + l*NF, ln_b + l*NF,
        in_w + (size_t)l*2*NF*NF, in_b + l*2*NF, xcr, zb);
    k_conv_scan1<<<BKS*NCH, 256, 0, stream>>>(xcr, conv_w + (size_t)l*NF*4, conv_b + l*NF,
        xp_w + (size_t)l*32*NF, dtp_w + (size_t)l*NF*RD, dtp_b + l*NF,
        A_log + (size_t)l*NF*SD, xcc, dtb, Bmb, Cmb, ap, hfb);
    k_scan_combine<<<BKS, NF, 0, stream>>>(ap, hfb, hinit);
    k_scan_pass2<<<BKS*NCH, NF, 0, stream>>>(dtb, xcc, Bmb, Cmb, A_log + (size_t)l*NF*SD,
        hinit, zb, Dv + l*NF, yb);
    k_gate_out<<<NBLK, 256, 0, stream>>>(yb, out_w + (size_t)l*NF*NF, out_b + l*NF, seq);
  }
  k_cross_gemm<<<NBLK, 256, 0, stream>>>(seq, cb_w, cb_b, cross);
  k_cross_ln<<<NTOK/32, 256, 0, stream>>>(seq, cross, cb_ln_w, cb_ln_b, fin_ln_w, fin_ln_b, out);
}